// Round 9
// baseline (170.451 us; speedup 1.0000x reference)
//
#include <hip/hip_runtime.h>

#define B_  2048
#define I_  256
#define H_  512
#define D_  768
#define K_  32

typedef unsigned short ushort_t;
typedef unsigned int uint_t;
typedef __attribute__((ext_vector_type(8))) __bf16 bf16x8;
typedef __attribute__((ext_vector_type(4))) float f32x4;

__device__ __forceinline__ ushort_t f2bf(float f) {
  uint_t u = __float_as_uint(f);
  u += 0x7fffu + ((u >> 16) & 1u);   // RNE
  return (ushort_t)(u >> 16);
}
__device__ __forceinline__ float fast_sigmoid(float x) {
  return 1.f / (1.f + __expf(-x));
}
__device__ __forceinline__ float fast_tanh(float x) {
  float t = __expf(2.f * fabsf(x));          // overflow -> inf -> r = 1
  float r = 1.f - 2.f / (t + 1.f);
  return copysignf(r, x);
}
__device__ __forceinline__ void gload16(const void* g, void* l) {
  __builtin_amdgcn_global_load_lds(
      (const __attribute__((address_space(1))) void*)g,
      (__attribute__((address_space(3))) void*)l, 16, 0, 0);
}
// runtime 0 the compiler can't fold -> defeats cross-rep CSE in the
// instrumentation repeat loops (this round is a measurement round)
__device__ __forceinline__ int opaque_zero() {
  int z;
  asm volatile("s_mov_b32 %0, 0" : "=s"(z));
  return z;
}

// ---- transposes (instrumented x24): blocks 0..287: W1,b1,W2 -> [g][k][d] fp32;
//      blocks 288..1823: Wc -> wcT [g][h][d] bf16 ----
__global__ __launch_bounds__(256) void transpose_all(
    const float* __restrict__ W1, const float* __restrict__ b1,
    const float* __restrict__ W2, const float* __restrict__ Wc,
    float* __restrict__ w1t, float* __restrict__ b1t, float* __restrict__ w2t,
    ushort_t* __restrict__ wcT) {
  __shared__ float t[32][33];
  int tx = threadIdx.x & 31, ty = threadIdx.x >> 5;
  int bid = blockIdx.x;
  const int z = opaque_zero();
#pragma unroll 1
  for (int rep = 0; rep < 24; ++rep) {
    const size_t zr = (size_t)(z * rep);
    if (bid < 288) {
      int zi = bid / 96;               // 0:W1 1:b1 2:W2
      int g = (bid / 24) % 4;
      int d0 = (bid % 24) * 32;
      const float* src = ((zi == 0) ? W1 : (zi == 1) ? b1 : W2) + zr;
      float* dst       = (zi == 0) ? w1t : (zi == 1) ? b1t : w2t;
#pragma unroll
      for (int i = 0; i < 4; ++i) {
        int r = ty + i * 8;
        t[r][tx] = src[((size_t)g * D_ + d0 + r) * K_ + tx];
      }
      __syncthreads();
#pragma unroll
      for (int i = 0; i < 4; ++i) {
        int r = ty + i * 8;                   // k index
        dst[((size_t)g * K_ + r) * D_ + d0 + tx] = t[tx][r];
      }
    } else {
      int r2 = bid - 288;
      int g = r2 / 384;
      int rem = r2 % 384;
      int d0 = (rem / 16) * 32;
      int h0 = (rem % 16) * 32;
      const float* Wcr = Wc + zr;
#pragma unroll
      for (int i = 0; i < 4; ++i) {
        int r = ty + i * 8;
        t[r][tx] = Wcr[((size_t)g * D_ + d0 + r) * H_ + h0 + tx];
      }
      __syncthreads();
#pragma unroll
      for (int i = 0; i < 4; ++i) {
        int r = ty + i * 8;                   // h index
        wcT[((size_t)g * H_ + h0 + r) * D_ + d0 + tx] = f2bf(t[tx][r]);
      }
    }
    __syncthreads();
  }
}

// ---- MLP (instrumented x6): k-chunk-streamed weights, j=32 batch block ----
__global__ __launch_bounds__(256) void kan_mlp(
    const float* __restrict__ x, const float* __restrict__ hp,
    const float* __restrict__ w1t, const float* __restrict__ b1t,
    const float* __restrict__ w2t, const float* __restrict__ b2,
    ushort_t* __restrict__ uT) {
  int bi = blockIdx.x;
  int combo = bi >> 6;               // 0..11
  int bc = bi & 63;                  // batch chunk, 32 rows
  int g = combo & 3;
  int dc = combo >> 2;               // 0: x[:,0:256], 1: hp[:,0:256], 2: hp[:,256:512]
  int t = threadIdx.x;
  int d = dc * 256 + t;

  const float* src0 = (dc == 0) ? (x + t) : (hp + ((dc == 1) ? t : t + 256));
  int stride = (dc == 0) ? I_ : H_;
  int b0 = bc * 32;
  const int z = opaque_zero();

#pragma unroll 1
  for (int rep = 0; rep < 6; ++rep) {
    const size_t zr = (size_t)(z * rep);
    const float* src = src0 + zr;
    float cv[32], acc[32];
    float bias = b2[(size_t)g * D_ + d + zr];
#pragma unroll
    for (int j = 0; j < 32; ++j) {
      cv[j] = src[(size_t)(b0 + j) * stride];
      acc[j] = bias;
    }
    const float* w1p = w1t + (size_t)g * K_ * D_ + d + zr;
    const float* b1p = b1t + (size_t)g * K_ * D_ + d + zr;
    const float* w2p = w2t + (size_t)g * K_ * D_ + d + zr;
#pragma unroll 1
    for (int kc = 0; kc < K_; kc += 4) {
      float w1c[4], b1c[4], w2c[4];
#pragma unroll
      for (int e = 0; e < 4; ++e) {
        w1c[e] = w1p[(size_t)(kc + e) * D_];
        b1c[e] = b1p[(size_t)(kc + e) * D_];
        w2c[e] = w2p[(size_t)(kc + e) * D_];
      }
#pragma unroll
      for (int e = 0; e < 4; ++e)
#pragma unroll
        for (int j = 0; j < 32; ++j) {
          float h = fmaxf(fmaf(cv[j], w1c[e], b1c[e]), 0.f);
          acc[j] = fmaf(h, w2c[e], acc[j]);
        }
    }
    ushort_t* up = uT + (size_t)g * B_ * D_ + (size_t)b0 * D_ + d;
#pragma unroll
    for (int j = 0; j < 32; ++j) up[(size_t)j * D_] = f2bf(acc[j]);
  }
}

// ---- phase 2 v7 (instrumented x3): 64x64x4g, 16 waves, 256 blocks,
//      NBUF=4 counted-vmcnt global_load_lds pipeline, fused LSTM ----
#define TBM 64
#define THN 64
#define BK2 32
#define NT2 (D_ / BK2)               // 24
#define AREG 16384
#define BUF2 32768
#define NBUF2 4

__global__ __launch_bounds__(1024, 4) void kan_phase2(
    const ushort_t* __restrict__ uT, const ushort_t* __restrict__ wcT,
    const float* __restrict__ bc, const float* __restrict__ cprev,
    float* __restrict__ out) {
  __shared__ __align__(16) char smem[NBUF2 * BUF2];   // 131072 B
  const int b0 = blockIdx.x * TBM;
  const int h0 = blockIdx.y * THN;
  const int t = threadIdx.x;
  const int w = t >> 6;
  const int l = t & 63;
  const int g = w >> 2, mh = w & 3;
  const int frow = l & 15, c0 = l >> 4;

  const int srow = t >> 2, sc = t & 3;
  const int sg = srow >> 6, sr = srow & 63;
  const int scg = sc ^ ((sr ^ (sr >> 2)) & 3);
  const ushort_t* asrc0 = uT + ((size_t)sg * B_ + b0 + sr) * D_ + scg * 8;
  const ushort_t* bsrc0 = wcT + ((size_t)sg * H_ + h0 + sr) * D_ + scg * 8;
  const int aLds = t * 16;
  const int bLds = AREG + t * 16;

  const int key = (frow ^ (frow >> 2)) & 3;
  const int cx = ((c0 ^ key) << 4);
  const int aoff = ((g * 64 + mh * 16 + frow) << 6) + cx;
  int boff[4];
#pragma unroll
  for (int n = 0; n < 4; ++n)
    boff[n] = AREG + ((g * 64 + n * 16 + frow) << 6) + cx;

  const int z = opaque_zero();

#pragma unroll 1
  for (int rep = 0; rep < 3; ++rep) {
    const size_t zr = (size_t)(z * rep);
    const ushort_t* asrc = asrc0 + zr;
    const ushort_t* bsrc = bsrc0 + zr;

    f32x4 acc[4];
#pragma unroll
    for (int n = 0; n < 4; ++n) {
      float bv = bc[(size_t)g * H_ + h0 + n * 16 + frow + zr];
      acc[n] = (f32x4){bv, bv, bv, bv};
    }

    auto stage = [&](int bufoff, int ke) {
      gload16(asrc + ke, smem + bufoff + aLds);
      gload16(bsrc + ke, smem + bufoff + bLds);
    };
    auto compute = [&](const char* bb) {
      bf16x8 af = *(const bf16x8*)(bb + aoff);
      bf16x8 bf[4];
#pragma unroll
      for (int n = 0; n < 4; ++n) bf[n] = *(const bf16x8*)(bb + boff[n]);
      __builtin_amdgcn_s_setprio(1);
#pragma unroll
      for (int n = 0; n < 4; ++n)
        acc[n] = __builtin_amdgcn_mfma_f32_16x16x32_bf16(af, bf[n], acc[n], 0, 0, 0);
      __builtin_amdgcn_s_setprio(0);
    };

    stage(0 * BUF2, 0 * BK2);
    stage(1 * BUF2, 1 * BK2);
    stage(2 * BUF2, 2 * BK2);
    int s = 0;
#pragma unroll 1
    for (; s < NT2 - 3; ++s) {
      asm volatile("s_waitcnt vmcnt(4)" ::: "memory");
      __builtin_amdgcn_s_barrier();
      stage(((s + 3) & 3) * BUF2, (s + 3) * BK2);
      compute(smem + (s & 3) * BUF2);
    }
    asm volatile("s_waitcnt vmcnt(4)" ::: "memory");   // s = NT2-3
    __builtin_amdgcn_s_barrier();
    compute(smem + (s & 3) * BUF2);
    ++s;
    asm volatile("s_waitcnt vmcnt(2)" ::: "memory");   // s = NT2-2
    __builtin_amdgcn_s_barrier();
    compute(smem + (s & 3) * BUF2);
    ++s;
    asm volatile("s_waitcnt vmcnt(0)" ::: "memory");   // s = NT2-1
    __builtin_amdgcn_s_barrier();
    compute(smem + (s & 3) * BUF2);
    __syncthreads();                   // MFMA LDS reads done before gf overlay

    float* gf = (float*)smem;
#pragma unroll
    for (int n = 0; n < 4; ++n)
#pragma unroll
      for (int e = 0; e < 4; ++e) {
        int row = mh * 16 + c0 * 4 + e;
        int col = n * 16 + frow;
        gf[((size_t)g * 64 + row) * 68 + col] = acc[n][e];
      }
    __syncthreads();

    {
      int row = t >> 4;                // 0..63
      int ch = t & 15;
      int b = b0 + row;
      int hc = h0 + ch * 4;
      f32x4 g0 = *(const f32x4*)&gf[((size_t)0 * 64 + row) * 68 + ch * 4];
      f32x4 g1 = *(const f32x4*)&gf[((size_t)1 * 64 + row) * 68 + ch * 4];
      f32x4 g2 = *(const f32x4*)&gf[((size_t)2 * 64 + row) * 68 + ch * 4];
      f32x4 g3 = *(const f32x4*)&gf[((size_t)3 * 64 + row) * 68 + ch * 4];
      f32x4 cp = *(const f32x4*)&cprev[(size_t)b * H_ + hc];
      f32x4 hv, cv;
#pragma unroll
      for (int e = 0; e < 4; ++e) {
        float ft = fast_sigmoid(g0[e]);
        float it = fast_sigmoid(g1[e]);
        float ot = fast_sigmoid(g2[e]);
        float tc = fast_tanh(g3[e]);
        float cn = ft * cp[e] + it * tc;
        cv[e] = cn;
        hv[e] = ot * fast_tanh(cn);
      }
      *(f32x4*)&out[(size_t)b * H_ + hc] = hv;
      *(f32x4*)&out[(size_t)B_ * H_ + (size_t)b * H_ + hc] = cv;
    }
    __syncthreads();                   // gf reads done before next rep stages
  }
}

extern "C" void kernel_launch(void* const* d_in, const int* in_sizes, int n_in,
                              void* d_out, int out_size, void* d_ws, size_t ws_size,
                              hipStream_t stream) {
  const float* x  = (const float*)d_in[0];
  const float* hp = (const float*)d_in[1];
  const float* cp = (const float*)d_in[2];
  const float* W1 = (const float*)d_in[3];
  const float* b1 = (const float*)d_in[4];
  const float* W2 = (const float*)d_in[5];
  const float* b2 = (const float*)d_in[6];
  const float* Wc = (const float*)d_in[7];
  const float* bc = (const float*)d_in[8];
  float* out = (float*)d_out;

  // workspace layout
  float* w1t = (float*)d_ws;                        // 4*32*768 f
  float* b1t = w1t + 98304;
  float* w2t = b1t + 98304;
  ushort_t* wcT = (ushort_t*)(w2t + 98304);         // 4*512*768 bf16
  ushort_t* uT  = wcT + (size_t)4 * H_ * D_;        // 4*2048*768 bf16

  transpose_all<<<1824, 256, 0, stream>>>(W1, b1, W2, Wc, w1t, b1t, w2t, wcT);
  kan_mlp<<<768, 256, 0, stream>>>(x, hp, w1t, b1t, w2t, b2, uT);
  kan_phase2<<<dim3(B_ / TBM, H_ / THN), 1024, 0, stream>>>(uT, wcT, bc, cp, out);
}

// Round 10
// 46.087 us; speedup vs baseline: 3.6985x; 3.6985x over previous
//
#include <hip/hip_runtime.h>
#include <hip/hip_fp16.h>

#define B_  2048
#define I_  256
#define H_  512
#define D_  768
#define K_  32

typedef unsigned short ushort_t;
typedef unsigned int uint_t;
typedef __attribute__((ext_vector_type(8))) __bf16 bf16x8;
typedef __attribute__((ext_vector_type(4))) float f32x4;

__device__ __forceinline__ ushort_t f2bf(float f) {
  uint_t u = __float_as_uint(f);
  u += 0x7fffu + ((u >> 16) & 1u);   // RNE
  return (ushort_t)(u >> 16);
}
__device__ __forceinline__ float fast_sigmoid(float x) {
  return 1.f / (1.f + __expf(-x));
}
__device__ __forceinline__ float fast_tanh(float x) {
  float t = __expf(2.f * fabsf(x));          // overflow -> inf -> r = 1
  float r = 1.f - 2.f / (t + 1.f);
  return copysignf(r, x);
}
__device__ __forceinline__ void gload16(const void* g, void* l) {
  __builtin_amdgcn_global_load_lds(
      (const __attribute__((address_space(1))) void*)g,
      (__attribute__((address_space(3))) void*)l, 16, 0, 0);
}
__device__ __forceinline__ __half2 pk_max(__half2 a, __half2 b) {
  __half2 r;
  asm("v_pk_max_f16 %0, %1, %2" : "=v"(r) : "v"(a), "v"(b));
  return r;
}

// ---- transposes: blocks 0..287: W1,b1,W2 [g][d][k] -> packed half2 [g][k/2][d];
//      blocks 288..1823: Wc [g][d][h] -> wcT [g][h][d] bf16 ----
__global__ __launch_bounds__(256) void transpose_all(
    const float* __restrict__ W1, const float* __restrict__ b1,
    const float* __restrict__ W2, const float* __restrict__ Wc,
    __half2* __restrict__ w1h, __half2* __restrict__ b1h, __half2* __restrict__ w2h,
    ushort_t* __restrict__ wcT) {
  __shared__ float t[32][33];
  int tx = threadIdx.x & 31, ty = threadIdx.x >> 5;
  int bid = blockIdx.x;
  if (bid < 288) {
    int z = bid / 96;                 // 0:W1 1:b1 2:W2
    int g = (bid / 24) % 4;
    int d0 = (bid % 24) * 32;
    const float* src = (z == 0) ? W1 : (z == 1) ? b1 : W2;
    __half2* dst     = (z == 0) ? w1h : (z == 1) ? b1h : w2h;
#pragma unroll
    for (int i = 0; i < 4; ++i) {
      int r = ty + i * 8;                     // d-local row
      t[r][tx] = src[((size_t)g * D_ + d0 + r) * K_ + tx];
    }
    __syncthreads();
#pragma unroll
    for (int i = 0; i < 2; ++i) {
      int r2 = ty + i * 8;                    // k-pair index 0..15
      __half2 v = __halves2half2(__float2half_rn(t[tx][2 * r2]),
                                 __float2half_rn(t[tx][2 * r2 + 1]));
      dst[((size_t)g * (K_ / 2) + r2) * D_ + d0 + tx] = v;
    }
  } else {
    int r2 = bid - 288;
    int g = r2 / 384;
    int rem = r2 % 384;
    int d0 = (rem / 16) * 32;
    int h0 = (rem % 16) * 32;
#pragma unroll
    for (int i = 0; i < 4; ++i) {
      int r = ty + i * 8;
      t[r][tx] = Wc[((size_t)g * D_ + d0 + r) * H_ + h0 + tx];
    }
    __syncthreads();
#pragma unroll
    for (int i = 0; i < 4; ++i) {
      int r = ty + i * 8;                     // h index
      wcT[((size_t)g * H_ + h0 + r) * D_ + d0 + tx] = f2bf(t[tx][r]);
    }
  }
}

// ---- MLP (phase 1) v4: packed fp16 k-pair math (v_pk_fma_f16 / v_pk_max_f16),
//      1.5 VALU ops per (b,d,k) vs 3 in fp32; j=32 batch block, lane = d ----
__global__ __launch_bounds__(256) void kan_mlp(
    const float* __restrict__ x, const float* __restrict__ hp,
    const __half2* __restrict__ w1h, const __half2* __restrict__ b1h,
    const __half2* __restrict__ w2h, const float* __restrict__ b2,
    ushort_t* __restrict__ uT) {
  int bi = blockIdx.x;
  int combo = bi >> 6;               // 0..11
  int bc = bi & 63;                  // batch chunk, 32 rows
  int g = combo & 3;
  int dc = combo >> 2;               // 0: x[:,0:256], 1: hp[:,0:256], 2: hp[:,256:512]
  int t = threadIdx.x;
  int d = dc * 256 + t;

  const float* src = (dc == 0) ? (x + t) : (hp + ((dc == 1) ? t : t + 256));
  int stride = (dc == 0) ? I_ : H_;
  int b0 = bc * 32;

  const __half2 z2 = __halves2half2(__float2half_rn(0.f), __float2half_rn(0.f));
  __half2 cv2[32], acc2[32];
#pragma unroll
  for (int j = 0; j < 32; ++j) {
    float c = src[(size_t)(b0 + j) * stride];
    cv2[j] = __half2half2(__float2half_rn(c));
    acc2[j] = z2;
  }

  const __half2* w1p = w1h + (size_t)g * (K_ / 2) * D_ + d;   // [k2][d], coalesced
  const __half2* b1p = b1h + (size_t)g * (K_ / 2) * D_ + d;
  const __half2* w2p = w2h + (size_t)g * (K_ / 2) * D_ + d;

  for (int kc = 0; kc < K_ / 2; kc += 4) {    // stream 4 k-pairs: 12 live regs
    __half2 w1c[4], b1c[4], w2c[4];
#pragma unroll
    for (int e = 0; e < 4; ++e) {
      w1c[e] = w1p[(size_t)(kc + e) * D_];
      b1c[e] = b1p[(size_t)(kc + e) * D_];
      w2c[e] = w2p[(size_t)(kc + e) * D_];
    }
#pragma unroll
    for (int e = 0; e < 4; ++e)
#pragma unroll
      for (int j = 0; j < 32; ++j) {
        __half2 t2 = __hfma2(cv2[j], w1c[e], b1c[e]);
        __half2 h2 = pk_max(t2, z2);
        acc2[j] = __hfma2(h2, w2c[e], acc2[j]);
      }
  }

  float bias = b2[(size_t)g * D_ + d];
  ushort_t* up = uT + (size_t)g * B_ * D_ + (size_t)b0 * D_ + d;
#pragma unroll
  for (int j = 0; j < 32; ++j) {
    float u = bias + __half2float(__low2half(acc2[j])) +
              __half2float(__high2half(acc2[j]));
    up[(size_t)j * D_] = f2bf(u);
  }
}

// ---- phase 2 v7 (UNCHANGED anchor): 64(b) x 64(h) x 4 gates per block,
//      16 waves, 256 blocks, NBUF=4 counted-vmcnt global_load_lds pipeline,
//      fused LSTM epilogue ----
#define TBM 64
#define THN 64
#define BK2 32
#define NT2 (D_ / BK2)               // 24
#define AREG 16384                   // A region bytes per buffer
#define BUF2 32768                   // per-buffer total (A 16K + B 16K)
#define NBUF2 4

__global__ __launch_bounds__(1024, 4) void kan_phase2(
    const ushort_t* __restrict__ uT, const ushort_t* __restrict__ wcT,
    const float* __restrict__ bc, const float* __restrict__ cprev,
    float* __restrict__ out) {
  __shared__ __align__(16) char smem[NBUF2 * BUF2];   // 131072 B
  const int b0 = blockIdx.x * TBM;
  const int h0 = blockIdx.y * THN;
  const int t = threadIdx.x;
  const int w = t >> 6;
  const int l = t & 63;
  const int g = w >> 2, mh = w & 3;    // wave = (gate, b-quarter)
  const int frow = l & 15, c0 = l >> 4;

  const int srow = t >> 2, sc = t & 3;
  const int sg = srow >> 6, sr = srow & 63;
  const int scg = sc ^ ((sr ^ (sr >> 2)) & 3);
  const ushort_t* asrc = uT + ((size_t)sg * B_ + b0 + sr) * D_ + scg * 8;
  const ushort_t* bsrc = wcT + ((size_t)sg * H_ + h0 + sr) * D_ + scg * 8;
  const int aLds = t * 16;
  const int bLds = AREG + t * 16;

  const int key = (frow ^ (frow >> 2)) & 3;
  const int cx = ((c0 ^ key) << 4);
  const int aoff = ((g * 64 + mh * 16 + frow) << 6) + cx;
  int boff[4];
#pragma unroll
  for (int n = 0; n < 4; ++n)
    boff[n] = AREG + ((g * 64 + n * 16 + frow) << 6) + cx;

  f32x4 acc[4];
#pragma unroll
  for (int n = 0; n < 4; ++n) {
    float bv = bc[(size_t)g * H_ + h0 + n * 16 + frow];
    acc[n] = (f32x4){bv, bv, bv, bv};
  }

  auto stage = [&](int bufoff, int ke) {
    gload16(asrc + ke, smem + bufoff + aLds);
    gload16(bsrc + ke, smem + bufoff + bLds);
  };
  auto compute = [&](const char* bb) {
    bf16x8 af = *(const bf16x8*)(bb + aoff);
    bf16x8 bf[4];
#pragma unroll
    for (int n = 0; n < 4; ++n) bf[n] = *(const bf16x8*)(bb + boff[n]);
    __builtin_amdgcn_s_setprio(1);
#pragma unroll
    for (int n = 0; n < 4; ++n)
      acc[n] = __builtin_amdgcn_mfma_f32_16x16x32_bf16(af, bf[n], acc[n], 0, 0, 0);
    __builtin_amdgcn_s_setprio(0);
  };

  stage(0 * BUF2, 0 * BK2);
  stage(1 * BUF2, 1 * BK2);
  stage(2 * BUF2, 2 * BK2);
  int s = 0;
  for (; s < NT2 - 3; ++s) {
    asm volatile("s_waitcnt vmcnt(4)" ::: "memory");
    __builtin_amdgcn_s_barrier();
    stage(((s + 3) & 3) * BUF2, (s + 3) * BK2);
    compute(smem + (s & 3) * BUF2);
  }
  asm volatile("s_waitcnt vmcnt(4)" ::: "memory");   // s = NT2-3
  __builtin_amdgcn_s_barrier();
  compute(smem + (s & 3) * BUF2);
  ++s;
  asm volatile("s_waitcnt vmcnt(2)" ::: "memory");   // s = NT2-2
  __builtin_amdgcn_s_barrier();
  compute(smem + (s & 3) * BUF2);
  ++s;
  asm volatile("s_waitcnt vmcnt(0)" ::: "memory");   // s = NT2-1
  __builtin_amdgcn_s_barrier();
  compute(smem + (s & 3) * BUF2);
  __syncthreads();

  float* gf = (float*)smem;
#pragma unroll
  for (int n = 0; n < 4; ++n)
#pragma unroll
    for (int e = 0; e < 4; ++e) {
      int row = mh * 16 + c0 * 4 + e;
      int col = n * 16 + frow;
      gf[((size_t)g * 64 + row) * 68 + col] = acc[n][e];
    }
  __syncthreads();

  {
    int row = t >> 4;                  // 0..63
    int ch = t & 15;
    int b = b0 + row;
    int hc = h0 + ch * 4;
    f32x4 g0 = *(const f32x4*)&gf[((size_t)0 * 64 + row) * 68 + ch * 4];
    f32x4 g1 = *(const f32x4*)&gf[((size_t)1 * 64 + row) * 68 + ch * 4];
    f32x4 g2 = *(const f32x4*)&gf[((size_t)2 * 64 + row) * 68 + ch * 4];
    f32x4 g3 = *(const f32x4*)&gf[((size_t)3 * 64 + row) * 68 + ch * 4];
    f32x4 cp = *(const f32x4*)&cprev[(size_t)b * H_ + hc];
    f32x4 hv, cv;
#pragma unroll
    for (int e = 0; e < 4; ++e) {
      float ft = fast_sigmoid(g0[e]);
      float it = fast_sigmoid(g1[e]);
      float ot = fast_sigmoid(g2[e]);
      float tc = fast_tanh(g3[e]);
      float cn = ft * cp[e] + it * tc;
      cv[e] = cn;
      hv[e] = ot * fast_tanh(cn);
    }
    *(f32x4*)&out[(size_t)b * H_ + hc] = hv;
    *(f32x4*)&out[(size_t)B_ * H_ + (size_t)b * H_ + hc] = cv;
  }
}

extern "C" void kernel_launch(void* const* d_in, const int* in_sizes, int n_in,
                              void* d_out, int out_size, void* d_ws, size_t ws_size,
                              hipStream_t stream) {
  const float* x  = (const float*)d_in[0];
  const float* hp = (const float*)d_in[1];
  const float* cp = (const float*)d_in[2];
  const float* W1 = (const float*)d_in[3];
  const float* b1 = (const float*)d_in[4];
  const float* W2 = (const float*)d_in[5];
  const float* b2 = (const float*)d_in[6];
  const float* Wc = (const float*)d_in[7];
  const float* bc = (const float*)d_in[8];
  float* out = (float*)d_out;

  // workspace layout
  __half2* w1h = (__half2*)d_ws;                    // 4*16*768 half2
  __half2* b1h = w1h + (size_t)4 * (K_ / 2) * D_;
  __half2* w2h = b1h + (size_t)4 * (K_ / 2) * D_;
  ushort_t* wcT = (ushort_t*)(w2h + (size_t)4 * (K_ / 2) * D_);  // 4*512*768 bf16
  ushort_t* uT  = wcT + (size_t)4 * H_ * D_;        // 4*2048*768 bf16

  transpose_all<<<1824, 256, 0, stream>>>(W1, b1, W2, Wc, w1h, b1h, w2h, wcT);
  kan_mlp<<<768, 256, 0, stream>>>(x, hp, w1h, b1h, w2h, b2, uT);
  kan_phase2<<<dim3(B_ / TBM, H_ / THN), 1024, 0, stream>>>(uT, wcT, bc, cp, out);
}